// Round 2
// baseline (89.227 us; speedup 1.0000x reference)
//
#include <hip/hip_runtime.h>

#define M_HALF 16384
#define D 128
#define C 64
#define EPSF 1e-5f

#define K1_BLOCKS 64
#define ROWS_PER_K1 (M_HALF / K1_BLOCKS)   // 256
#define K3_ROWS_PER_BLOCK 16
#define K3_BLOCKS (M_HALF / K3_ROWS_PER_BLOCK) // 1024

// ---------------- Kernel 1: per-block prototype partial sums ----------------
__global__ __launch_bounds__(256) void proto_partial_kernel(
    const float* __restrict__ x, const int* __restrict__ y,
    float* __restrict__ partials,      // [K1_BLOCKS][C*D]
    float* __restrict__ cnt_partials)  // [K1_BLOCKS][C]
{
    __shared__ float proto_s[C * D];   // 32 KB
    __shared__ float cnt_s[C];
    const int tid = threadIdx.x;
    for (int i = tid; i < C * D; i += 256) proto_s[i] = 0.f;
    if (tid < C) cnt_s[tid] = 0.f;
    __syncthreads();

    const int row_base = blockIdx.x * ROWS_PER_K1;
    const int k    = tid & (D - 1);
    const int rsub = tid >> 7;         // 0 or 1 (two rows in flight)
    for (int r = 0; r < ROWS_PER_K1; r += 2) {
        const int row = row_base + r + rsub;
        const int cls = y[row];
        const float v = x[(size_t)row * D + k];
        atomicAdd(&proto_s[cls * D + k], v);
        if (k == 0) atomicAdd(&cnt_s[cls], 1.f);
    }
    __syncthreads();

    float* outp = partials + (size_t)blockIdx.x * (C * D);
    for (int i = tid; i < C * D; i += 256) outp[i] = proto_s[i];
    if (tid < C) cnt_partials[blockIdx.x * C + tid] = cnt_s[tid];
}

// ---------------- Kernel 2: reduce partials, divide, store transposed -------
__global__ __launch_bounds__(256) void proto_finalize_kernel(
    const float* __restrict__ partials,
    const float* __restrict__ cnt_partials,
    float* __restrict__ protoT)        // [D][C]  (k-major, class minor)
{
    const int tid = blockIdx.x * blockDim.x + threadIdx.x; // 0..C*D-1
    const int c = tid >> 7;            // /D
    const int k = tid & (D - 1);
    float sum = 0.f, cnt = 0.f;
    #pragma unroll 4
    for (int b = 0; b < K1_BLOCKS; ++b) {
        sum += partials[(size_t)b * (C * D) + c * D + k];
        cnt += cnt_partials[b * C + c];
    }
    if (cnt < 0.5f) cnt = 1.f;         // class_counts + (counts < 0.01)
    protoT[k * C + c] = sum / cnt;
}

// ---------------- Kernel 3: distances + logsumexp + per-block loss ----------
__device__ inline float sqsign(float xv, float p) {
    const float d = xv - p;
    const float t = d + EPSF;
    const float s = t * t;                 // exp(2*log(|d+eps|)) == (d+eps)^2
    const float sg = (d > 0.f) ? 1.f : ((d < 0.f) ? -1.f : 0.f);
    return sg * s;
}

__global__ __launch_bounds__(256) void dist_loss_kernel(
    const float* __restrict__ x, const int* __restrict__ y,
    const float* __restrict__ protoT,
    float* __restrict__ loss_partials)     // [K3_BLOCKS]
{
    __shared__ float pT[D * C];                    // 32 KB, [k][c]
    __shared__ float xrows[K3_ROWS_PER_BLOCK][D];  // 8 KB
    __shared__ float wsum[4];
    const int tid = threadIdx.x;

    { // stage transposed prototypes (coalesced float4)
        const float4* src = (const float4*)protoT;
        float4* dst = (float4*)pT;
        for (int i = tid; i < (D * C) / 4; i += 256) dst[i] = src[i];
    }
    const int row0_g = M_HALF + blockIdx.x * K3_ROWS_PER_BLOCK;
    { // stage 16 target rows
        const float4* src = (const float4*)(x + (size_t)row0_g * D);
        float4* dst = (float4*)&xrows[0][0];
        for (int i = tid; i < (K3_ROWS_PER_BLOCK * D) / 4; i += 256) dst[i] = src[i];
    }
    __syncthreads();

    const int lane = tid & 63;
    const int wid  = tid >> 6;        // 4 waves
    const int c    = lane;            // lane == class (C == 64 == wave size)
    const int r0   = wid * 4;         // each wave: 4 rows concurrently

    float a0 = 0.f, a1 = 0.f, a2 = 0.f, a3 = 0.f;
    #pragma unroll 4
    for (int k = 0; k < D; ++k) {
        const float p  = pT[k * C + c];        // 64 consecutive floats: free 2-way
        const float x0 = xrows[r0 + 0][k];     // uniform addr: LDS broadcast
        const float x1 = xrows[r0 + 1][k];
        const float x2 = xrows[r0 + 2][k];
        const float x3 = xrows[r0 + 3][k];
        a0 += sqsign(x0, p);
        a1 += sqsign(x1, p);
        a2 += sqsign(x2, p);
        a3 += sqsign(x3, p);
    }

    const float inv_d = 1.f / (float)D;
    float dist[4] = { -a0 * inv_d, -a1 * inv_d, -a2 * inv_d, -a3 * inv_d };

    float lsum = 0.f;
    #pragma unroll
    for (int r = 0; r < 4; ++r) {
        float dv = dist[r];
        float mx = dv;
        #pragma unroll
        for (int off = 32; off; off >>= 1) mx = fmaxf(mx, __shfl_xor(mx, off));
        float se = expf(dv - mx);
        #pragma unroll
        for (int off = 32; off; off >>= 1) se += __shfl_xor(se, off);
        const float lse = mx + logf(se);
        const int yt = y[row0_g + r0 + r];
        const float dy = __shfl(dv, yt);       // dist at true class
        lsum += lse - dy;                      // -logp[y]
    }

    if (lane == 0) wsum[wid] = lsum;           // lsum is wave-uniform
    __syncthreads();
    if (tid == 0)
        loss_partials[blockIdx.x] = wsum[0] + wsum[1] + wsum[2] + wsum[3];
}

// ---------------- Kernel 4: final scalar reduce -----------------------------
__global__ __launch_bounds__(256) void reduce_loss_kernel(
    const float* __restrict__ loss_partials, float* __restrict__ out)
{
    float s = 0.f;
    for (int i = threadIdx.x; i < K3_BLOCKS; i += 256) s += loss_partials[i];
    #pragma unroll
    for (int off = 32; off; off >>= 1) s += __shfl_xor(s, off);
    __shared__ float ws[4];
    const int lane = threadIdx.x & 63, wid = threadIdx.x >> 6;
    if (lane == 0) ws[wid] = s;
    __syncthreads();
    if (threadIdx.x == 0) out[0] = (ws[0] + ws[1] + ws[2] + ws[3]) / (float)M_HALF;
}

extern "C" void kernel_launch(void* const* d_in, const int* in_sizes, int n_in,
                              void* d_out, int out_size, void* d_ws, size_t ws_size,
                              hipStream_t stream) {
    const float* x = (const float*)d_in[0];   // [32768][128]
    const int*   y = (const int*)d_in[1];     // [32768]
    float* out = (float*)d_out;

    float* ws_f     = (float*)d_ws;
    float* partials = ws_f;                            // 64*8192 = 524288 f
    float* cntp     = partials + (size_t)K1_BLOCKS * C * D;  // 64*64
    float* protoT   = cntp + (size_t)K1_BLOCKS * C;          // 8192
    float* lossp    = protoT + (size_t)D * C;                // 1024

    proto_partial_kernel<<<K1_BLOCKS, 256, 0, stream>>>(x, y, partials, cntp);
    proto_finalize_kernel<<<(C * D) / 256, 256, 0, stream>>>(partials, cntp, protoT);
    dist_loss_kernel<<<K3_BLOCKS, 256, 0, stream>>>(x, y, protoT, lossp);
    reduce_loss_kernel<<<1, 256, 0, stream>>>(lossp, out);
}

// Round 3
// 65.550 us; speedup vs baseline: 1.3612x; 1.3612x over previous
//
#include <hip/hip_runtime.h>

#define M_HALF 16384
#define D 128
#define C 64

#define CNT_SLICES 64                      // count partial slices (256 rows each)
#define K3_ROWS_PER_BLOCK 16
#define K3_BLOCKS (M_HALF / K3_ROWS_PER_BLOCK) // 1024
#define PT_LD 65                           // padded leading dim for pT (bank-conflict-free)

// ---- Kernel A: zero proto accumulator + d_out, compute count partials ------
// blocks 0..31   : zero protoSum[8192]; block 0 also zeros out[0]
// blocks 32..95  : per-slice class counts (deterministic, no global atomics)
__global__ __launch_bounds__(256) void zero_count_kernel(
    const int* __restrict__ y,
    float* __restrict__ protoSum,      // [C][D]
    float* __restrict__ cnt_part,      // [C][CNT_SLICES]
    float* __restrict__ out)
{
    const int tid = threadIdx.x;
    const int b = blockIdx.x;
    if (b < 32) {
        protoSum[b * 256 + tid] = 0.f;
        if (b == 0 && tid == 0) out[0] = 0.f;
        return;
    }
    const int s = b - 32;                  // slice 0..63, rows [s*256, s*256+256)
    __shared__ float cnt_s[C];
    if (tid < C) cnt_s[tid] = 0.f;
    __syncthreads();
    const int cls = y[s * 256 + tid];
    atomicAdd(&cnt_s[cls], 1.f);
    __syncthreads();
    if (tid < C) cnt_part[tid * CNT_SLICES + s] = cnt_s[tid];
}

// ---- Kernel B: prototype accumulation via global fp32 atomics --------------
// 524288 threads: one float4 of x per thread, 4 atomicAdds to consecutive
// addresses (class-row-major dest -> few cache lines per wave).
__global__ __launch_bounds__(256) void proto_scatter_kernel(
    const float* __restrict__ x, const int* __restrict__ y,
    float* __restrict__ protoSum)      // [C][D]
{
    const int gid = blockIdx.x * 256 + threadIdx.x;   // 0 .. 524287
    const int row = gid >> 5;                         // support row
    const int kq  = gid & 31;                         // float4 index within row
    const int cls = y[row];
    const float4 v = ((const float4*)x)[gid];
    float* dst = protoSum + cls * D + kq * 4;
    atomicAdd(dst + 0, v.x);
    atomicAdd(dst + 1, v.y);
    atomicAdd(dst + 2, v.z);
    atomicAdd(dst + 3, v.w);
}

// ---- Kernel C: distances + logsumexp + atomic loss -------------------------
__global__ __launch_bounds__(256) void dist_loss_kernel(
    const float* __restrict__ x, const int* __restrict__ y,
    const float* __restrict__ protoSum, const float* __restrict__ cnt_part,
    float* __restrict__ out)
{
    __shared__ float pT[D * PT_LD];                // [k][c] padded, raw sums
    __shared__ float xrows[K3_ROWS_PER_BLOCK][D];  // 8 KB
    __shared__ float rcnt_s[C];                    // 1/count (fixed)
    __shared__ float wsum[4];
    const int tid = threadIdx.x;

    { // stage prototype sums transposed: src [c][k] -> pT[k][c]
        const float4* src = (const float4*)protoSum;
        for (int idx = tid; idx < (C * D) / 4; idx += 256) {
            const int c = idx >> 5;            // class
            const int kq = idx & 31;           // k/4
            const float4 v = src[idx];
            pT[(4 * kq + 0) * PT_LD + c] = v.x;
            pT[(4 * kq + 1) * PT_LD + c] = v.y;
            pT[(4 * kq + 2) * PT_LD + c] = v.z;
            pT[(4 * kq + 3) * PT_LD + c] = v.w;
        }
    }
    const int row0_g = M_HALF + blockIdx.x * K3_ROWS_PER_BLOCK;
    { // stage 16 target rows (linear, conflict-free)
        const float4* src = (const float4*)(x + (size_t)row0_g * D);
        float4* dst = (float4*)&xrows[0][0];
        for (int i = tid; i < (K3_ROWS_PER_BLOCK * D) / 4; i += 256) dst[i] = src[i];
    }
    if (tid < C) { // reduce count partials (L2-resident), fix, reciprocal
        const float4* cp = (const float4*)(cnt_part + tid * CNT_SLICES);
        float s = 0.f;
        #pragma unroll
        for (int j = 0; j < CNT_SLICES / 4; ++j) { float4 v = cp[j]; s += v.x + v.y + v.z + v.w; }
        if (s < 0.5f) s = 1.f;
        rcnt_s[tid] = 1.f / s;
    }
    __syncthreads();

    const int lane = tid & 63;
    const int wid  = tid >> 6;
    const int c    = lane;                 // lane == class
    const int r0   = wid * 4;              // each wave: 4 rows
    const float rc = rcnt_s[c];

    float a0 = 0.f, a1 = 0.f, a2 = 0.f, a3 = 0.f;
    #pragma unroll 2
    for (int k4 = 0; k4 < D / 4; ++k4) {
        // uniform-address float4 broadcasts of the 4 x-rows
        const float4 xv0 = *(const float4*)&xrows[r0 + 0][k4 * 4];
        const float4 xv1 = *(const float4*)&xrows[r0 + 1][k4 * 4];
        const float4 xv2 = *(const float4*)&xrows[r0 + 2][k4 * 4];
        const float4 xv3 = *(const float4*)&xrows[r0 + 3][k4 * 4];
        #pragma unroll
        for (int j = 0; j < 4; ++j) {
            const int k = k4 * 4 + j;
            const float p = pT[k * PT_LD + c] * rc;   // finalized prototype
            // sign(d)*(|d|+eps)^2 ~= d*|d|  (error ~2eps|d|, << threshold)
            const float d0 = ((const float*)&xv0)[j] - p; a0 = fmaf(d0, fabsf(d0), a0);
            const float d1 = ((const float*)&xv1)[j] - p; a1 = fmaf(d1, fabsf(d1), a1);
            const float d2 = ((const float*)&xv2)[j] - p; a2 = fmaf(d2, fabsf(d2), a2);
            const float d3 = ((const float*)&xv3)[j] - p; a3 = fmaf(d3, fabsf(d3), a3);
        }
    }

    const float ninv_d = -1.f / (float)D;
    float dist[4] = { a0 * ninv_d, a1 * ninv_d, a2 * ninv_d, a3 * ninv_d };

    float lsum = 0.f;
    #pragma unroll
    for (int r = 0; r < 4; ++r) {
        float dv = dist[r];
        float mx = dv;
        #pragma unroll
        for (int off = 32; off; off >>= 1) mx = fmaxf(mx, __shfl_xor(mx, off));
        float se = expf(dv - mx);
        #pragma unroll
        for (int off = 32; off; off >>= 1) se += __shfl_xor(se, off);
        const float lse = mx + logf(se);
        const int yt = y[row0_g + r0 + r];
        const float dy = __shfl(dv, yt);       // dist at true class
        lsum += lse - dy;                      // -logp[y]
    }

    if (lane == 0) wsum[wid] = lsum;           // wave-uniform
    __syncthreads();
    if (tid == 0) {
        const float tot = (wsum[0] + wsum[1] + wsum[2] + wsum[3]) * (1.f / (float)M_HALF);
        atomicAdd(out, tot);
    }
}

extern "C" void kernel_launch(void* const* d_in, const int* in_sizes, int n_in,
                              void* d_out, int out_size, void* d_ws, size_t ws_size,
                              hipStream_t stream) {
    const float* x = (const float*)d_in[0];   // [32768][128]
    const int*   y = (const int*)d_in[1];     // [32768]
    float* out = (float*)d_out;

    float* ws_f      = (float*)d_ws;
    float* protoSum  = ws_f;                          // C*D = 8192 floats
    float* cnt_part  = protoSum + C * D;              // C*CNT_SLICES = 4096 floats

    zero_count_kernel<<<96, 256, 0, stream>>>(y, protoSum, cnt_part, out);
    proto_scatter_kernel<<<(M_HALF * D / 4) / 256, 256, 0, stream>>>(x, y, protoSum);
    dist_loss_kernel<<<K3_BLOCKS, 256, 0, stream>>>(x, y, protoSum, cnt_part, out);
}

// Round 5
// 61.856 us; speedup vs baseline: 1.4425x; 1.0597x over previous
//
#include <hip/hip_runtime.h>

#define M_HALF 16384
#define D 128
#define C 64

#define K1_BLOCKS 256
#define K1_ROWS (M_HALF / K1_BLOCKS)   // 64 rows per block
#define LDK 65                          // [k][c] padded leading dim (floats)

#define K2_BLOCKS 32                    // 8192 threads: one per (k,c)

#define K3_ROWS 16
#define K3_BLOCKS (M_HALF / K3_ROWS)    // 1024
#define PT_LDQ 65                       // float4 leading dim for pT4

// ---- K1: per-block prototype partials (LDS accumulate, TLP-hidden) --------
__global__ __launch_bounds__(256) void k1_partials(
    const float* __restrict__ x, const int* __restrict__ y,
    float* __restrict__ partials,   // [K1_BLOCKS][D*C]  ([k][c] order)
    float* __restrict__ cnt_part,   // [K1_BLOCKS][C]
    float* __restrict__ out)
{
    __shared__ float proto_s[D * LDK];   // [k][c] padded: bank=(k+c)%32
    __shared__ float cnt_s[C];
    __shared__ int   ycls[K1_ROWS];
    const int tid = threadIdx.x;
    const int blk = blockIdx.x;

    for (int i = tid; i < D * LDK; i += 256) proto_s[i] = 0.f;
    if (tid < C) cnt_s[tid] = 0.f;
    const int base = blk * K1_ROWS;
    if (tid < K1_ROWS) ycls[tid] = y[base + tid];
    if (blk == 0 && tid == 0) out[0] = 0.f;    // zero loss accumulator (stream-ordered before K3)
    __syncthreads();

    const int row = tid >> 2;               // 64 rows, 4 threads each
    const int q   = tid & 3;                // quarter: 32 floats
    const int cls = ycls[row];
    const float4* xr = (const float4*)(x + (size_t)(base + row) * D) + q * 8;
    #pragma unroll
    for (int j = 0; j < 8; ++j) {
        const float4 v = xr[j];
        const int k = q * 32 + j * 4;
        atomicAdd(&proto_s[(k + 0) * LDK + cls], v.x);
        atomicAdd(&proto_s[(k + 1) * LDK + cls], v.y);
        atomicAdd(&proto_s[(k + 2) * LDK + cls], v.z);
        atomicAdd(&proto_s[(k + 3) * LDK + cls], v.w);
    }
    if (q == 0) atomicAdd(&cnt_s[cls], 1.f);
    __syncthreads();

    // write partials in [k][c] order: coalesced global, 2-way-free LDS reads
    float* outp = partials + (size_t)blk * (D * C);
    for (int i = tid; i < D * C; i += 256) {
        const int k = i >> 6, c = i & 63;
        outp[i] = proto_s[k * LDK + c];
    }
    if (tid < C) cnt_part[blk * C + tid] = cnt_s[tid];
}

// ---- K2: reduce partials, scale by 1/count, emit [k4][c] float4 table -----
__global__ __launch_bounds__(256) void k2_finalize(
    const float* __restrict__ partials, const float* __restrict__ cnt_part,
    float* __restrict__ pTg)        // layout: ((k4*64)+c)*4 + m  (k=4k4+m)
{
    __shared__ float rc_s[C];
    const int tid = threadIdx.x;
    const int idx = blockIdx.x * 256 + tid;     // 0..8191
    const int k = idx >> 6;
    const int c = idx & 63;

    if (tid < C) {                  // counts: sum 256 partials for class tid
        float s = 0.f;
        for (int b = 0; b < K1_BLOCKS; ++b) s += cnt_part[b * C + tid];
        if (s < 0.5f) s = 1.f;      // class_counts + (counts < 0.01)
        rc_s[tid] = 1.f / s;
    }
    __syncthreads();

    float s = 0.f;
    #pragma unroll 8
    for (int b = 0; b < K1_BLOCKS; ++b)
        s += partials[(size_t)b * (D * C) + k * C + c];   // coalesced per wave
    s *= rc_s[c];
    pTg[((k >> 2) * 64 + c) * 4 + (k & 3)] = s;
}

// ---- K3: distances + logsumexp + atomic loss ------------------------------
__global__ __launch_bounds__(256, 3) void k3_dist_loss(
    const float* __restrict__ x, const int* __restrict__ y,
    const float4* __restrict__ pTg4,   // [32][64] float4 finalized
    float* __restrict__ out)
{
    __shared__ float4 pT4[32 * PT_LDQ];        // 33280 B, [k4][c] padded
    __shared__ float xrows[K3_ROWS][D];        // 8 KB
    __shared__ float wsum[4];
    const int tid = threadIdx.x;

    for (int idx = tid; idx < 32 * 64; idx += 256) {
        const int k4 = idx >> 6, c = idx & 63;
        pT4[k4 * PT_LDQ + c] = pTg4[idx];      // coalesced read, std b128 write
    }
    const int row0 = M_HALF + blockIdx.x * K3_ROWS;
    {
        const float4* src = (const float4*)(x + (size_t)row0 * D);
        float4* dst = (float4*)&xrows[0][0];
        for (int i = tid; i < K3_ROWS * (D / 4); i += 256) dst[i] = src[i];
    }
    __syncthreads();

    const int lane = tid & 63;
    const int wid  = tid >> 6;
    const int c    = lane;          // lane == class
    const int r0   = wid * 4;       // 4 rows per wave

    float acc[4] = {0.f, 0.f, 0.f, 0.f};
    #pragma unroll 4
    for (int k4 = 0; k4 < 32; ++k4) {
        const float4 p4 = pT4[k4 * PT_LDQ + c];   // conflict-free b128
        #pragma unroll
        for (int r = 0; r < 4; ++r) {
            const float4 xv = *(const float4*)&xrows[r0 + r][k4 * 4]; // broadcast
            float d;
            d = xv.x - p4.x; acc[r] = fmaf(d, fabsf(d), acc[r]);
            d = xv.y - p4.y; acc[r] = fmaf(d, fabsf(d), acc[r]);
            d = xv.z - p4.z; acc[r] = fmaf(d, fabsf(d), acc[r]);
            d = xv.w - p4.w; acc[r] = fmaf(d, fabsf(d), acc[r]);
        }
    }

    const int yts = y[row0 + r0 + (lane & 3)];    // lane r<4 holds row r's label

    const float ninv_d = -1.f / (float)D;
    float lsum = 0.f;
    #pragma unroll
    for (int r = 0; r < 4; ++r) {
        float dv = acc[r] * ninv_d;
        float mx = dv;
        #pragma unroll
        for (int off = 32; off; off >>= 1) mx = fmaxf(mx, __shfl_xor(mx, off));
        float se = expf(dv - mx);
        #pragma unroll
        for (int off = 32; off; off >>= 1) se += __shfl_xor(se, off);
        const float lse = mx + logf(se);
        const int yt = __shfl(yts, r);            // true class of row r
        const float dy = __shfl(dv, yt);          // dist at true class
        lsum += lse - dy;
    }

    if (lane == 0) wsum[wid] = lsum;              // wave-uniform
    __syncthreads();
    if (tid == 0) {
        const float tot = (wsum[0] + wsum[1] + wsum[2] + wsum[3]) * (1.f / (float)M_HALF);
        atomicAdd(out, tot);
    }
}

extern "C" void kernel_launch(void* const* d_in, const int* in_sizes, int n_in,
                              void* d_out, int out_size, void* d_ws, size_t ws_size,
                              hipStream_t stream) {
    const float* x = (const float*)d_in[0];   // [32768][128]
    const int*   y = (const int*)d_in[1];     // [32768]
    float* out = (float*)d_out;

    float* ws_f     = (float*)d_ws;
    float* partials = ws_f;                              // 256*8192 floats = 8 MB
    float* cnt_part = partials + (size_t)K1_BLOCKS * D * C;   // 256*64
    float* pTg      = cnt_part + (size_t)K1_BLOCKS * C;       // 8192 floats

    k1_partials<<<K1_BLOCKS, 256, 0, stream>>>(x, y, partials, cnt_part, out);
    k2_finalize<<<K2_BLOCKS, 256, 0, stream>>>(partials, cnt_part, pTg);
    k3_dist_loss<<<K3_BLOCKS, 256, 0, stream>>>(x, y, (const float4*)pTg, out);
}